// Round 2
// baseline (186.087 us; speedup 1.0000x reference)
//
#include <hip/hip_runtime.h>
#include <hip/hip_bf16.h>
#include <math.h>

// Sizes (fixed by the reference problem)
#define BSZ 64
#define DV  1024
#define NQ  32
#define NS  1024
#define DD  128

#define ALPHA 0.5f
#define BG 4            // b-rows per multi block
#define CVT_BLOCKS 2048 // blocks doing fp32->bf16 in prep kernel

typedef __attribute__((ext_vector_type(8))) short short8;   // 8 bf16 = 4 VGPRs (MFMA A/B frag)
typedef __attribute__((ext_vector_type(4))) float floatx4;  // MFMA C/D frag

// ---------------- prep: fp32->bf16 convert (blocks < CVT_BLOCKS) + single-vector CE loss ----------------
__global__ void prep_kernel(const float* __restrict__ qm, const float* __restrict__ dm,
                            const float* __restrict__ qs, const float* __restrict__ ds,
                            unsigned short* __restrict__ qb, unsigned short* __restrict__ db,
                            float* __restrict__ svrow) {
    __shared__ float row[BSZ];
    if (blockIdx.x < CVT_BLOCKS) {
        const int QG = (BSZ * NQ * DD) / 4;   // 65536 float4 groups
        const int DG = (BSZ * NS * DD) / 4;   // 2097152
        int idx = blockIdx.x * blockDim.x + threadIdx.x;
        int stride = CVT_BLOCKS * blockDim.x;
        for (int g = idx; g < QG + DG; g += stride) {
            float4 v;
            unsigned short* dst;
            if (g < QG) { v = ((const float4*)qm)[g]; dst = qb + g * 4; }
            else        { int h = g - QG; v = ((const float4*)dm)[h]; dst = db + (size_t)h * 4; }
            __hip_bfloat16 a = __float2bfloat16(v.x);
            __hip_bfloat16 b = __float2bfloat16(v.y);
            __hip_bfloat16 c = __float2bfloat16(v.z);
            __hip_bfloat16 d = __float2bfloat16(v.w);
            ushort4 u;
            u.x = *(unsigned short*)&a; u.y = *(unsigned short*)&b;
            u.z = *(unsigned short*)&c; u.w = *(unsigned short*)&d;
            *(ushort4*)dst = u;
        }
    } else {
        // single-vector CE: scores[b][c] = qs[b].ds[c]; svrow[b] = lse_c - scores[b][b]
        int b = blockIdx.x - CVT_BLOCKS;     // 0..63
        int t = threadIdx.x;                 // 256
        int c = t >> 2, part = t & 3;
        const float4* qv = (const float4*)(qs + b * DV);
        const float4* dv = (const float4*)(ds + c * DV);
        float acc = 0.f;
        int k0 = part * 64;
#pragma unroll 8
        for (int k = k0; k < k0 + 64; ++k) {
            float4 a = qv[k], bb = dv[k];
            acc += a.x * bb.x + a.y * bb.y + a.z * bb.z + a.w * bb.w;
        }
        acc += __shfl_xor(acc, 1);
        acc += __shfl_xor(acc, 2);
        if (part == 0) row[c] = acc;
        __syncthreads();
        if (t < BSZ) {
            float v = row[t];
            float m = v;
#pragma unroll
            for (int o = 1; o < 64; o <<= 1) m = fmaxf(m, __shfl_xor(m, o));
            float e = expf(v - m);
#pragma unroll
            for (int o = 1; o < 64; o <<= 1) e += __shfl_xor(e, o);
            float lse = m + logf(e);
            if (t == 0) svrow[b] = lse - row[b];
        }
    }
}

// ---------------- multi-vector late-interaction scores via MFMA, LDS-free ----------------
// block = (bg, c): scores[bg*4 .. bg*4+3][c] = sum_n max_s ( Q[b,n,:] . D[c,s,:] )
// B-fragments are read straight from global (L2/L3-resident db), double-buffered in regs.
__launch_bounds__(256, 2)
__global__ void multi_scores_kernel(const unsigned short* __restrict__ qb,
                                    const unsigned short* __restrict__ db,
                                    float* __restrict__ scores) {
    int bg = blockIdx.x;         // 0..15
    int c  = blockIdx.y;         // 0..63
    int t  = threadIdx.x;        // 256
    int w  = t >> 6;             // wave 0..3
    int l  = t & 63;
    int lane16 = l & 15;
    int quad   = (l >> 4) & 3;

    __shared__ float smax[4][BG][NQ];   // per-wave partial row-maxes (tiny)

    // A fragments resident all kernel: A[m=lane&15][k=quad*8+j]
    short8 af[BG][2][4];
#pragma unroll
    for (int bi = 0; bi < BG; ++bi)
#pragma unroll
        for (int nt = 0; nt < 2; ++nt)
#pragma unroll
            for (int ks = 0; ks < 4; ++ks)
                af[bi][nt][ks] = *(const short8*)(qb +
                    ((size_t)((bg * BG + bi) * NQ + nt * 16 + lane16) * DD + ks * 32 + quad * 8));

    float mx[BG][2][4];
#pragma unroll
    for (int bi = 0; bi < BG; ++bi)
#pragma unroll
        for (int nt = 0; nt < 2; ++nt)
#pragma unroll
            for (int r = 0; r < 4; ++r) mx[bi][nt][r] = -1e30f;

    // wave w handles s-tiles st = w + 4*i, i = 0..15; B[n=lane&15][k=quad*8+j]
    const unsigned short* dptr = db + (size_t)c * NS * DD + (w * 16 + lane16) * DD + quad * 8;

    short8 bfA[4], bfB[4];
#pragma unroll
    for (int ks = 0; ks < 4; ++ks) bfA[ks] = *(const short8*)(dptr + ks * 32);

    auto tile_compute = [&](const short8* bf) {
        floatx4 acc[BG][2];
#pragma unroll
        for (int bi = 0; bi < BG; ++bi)
#pragma unroll
            for (int nt = 0; nt < 2; ++nt) acc[bi][nt] = (floatx4){0.f, 0.f, 0.f, 0.f};
#pragma unroll
        for (int ks = 0; ks < 4; ++ks)
#pragma unroll
            for (int bi = 0; bi < BG; ++bi)
#pragma unroll
                for (int nt = 0; nt < 2; ++nt)
                    acc[bi][nt] = __builtin_amdgcn_mfma_f32_16x16x32_bf16(
                        af[bi][nt][ks], bf[ks], acc[bi][nt], 0, 0, 0);
        // C/D layout: col(s)=lane&15, row(n)=quad*4+reg -> running max over s
#pragma unroll
        for (int bi = 0; bi < BG; ++bi)
#pragma unroll
            for (int nt = 0; nt < 2; ++nt)
#pragma unroll
                for (int r = 0; r < 4; ++r)
                    mx[bi][nt][r] = fmaxf(mx[bi][nt][r], acc[bi][nt][r]);
    };

#pragma unroll
    for (int i = 0; i < 16; i += 2) {
        if (i + 1 < 16) {
            const unsigned short* p = dptr + (size_t)(i + 1) * 64 * DD;
#pragma unroll
            for (int ks = 0; ks < 4; ++ks) bfB[ks] = *(const short8*)(p + ks * 32);
        }
        tile_compute(bfA);
        if (i + 2 < 16) {
            const unsigned short* p = dptr + (size_t)(i + 2) * 64 * DD;
#pragma unroll
            for (int ks = 0; ks < 4; ++ks) bfA[ks] = *(const short8*)(p + ks * 32);
        }
        tile_compute(bfB);
    }

    // max across the 16 lanes holding different s-columns
#pragma unroll
    for (int bi = 0; bi < BG; ++bi)
#pragma unroll
        for (int nt = 0; nt < 2; ++nt)
#pragma unroll
            for (int r = 0; r < 4; ++r) {
                float v = mx[bi][nt][r];
                v = fmaxf(v, __shfl_xor(v, 1));
                v = fmaxf(v, __shfl_xor(v, 2));
                v = fmaxf(v, __shfl_xor(v, 4));
                v = fmaxf(v, __shfl_xor(v, 8));
                mx[bi][nt][r] = v;
            }
    if (lane16 == 0) {
#pragma unroll
        for (int bi = 0; bi < BG; ++bi)
#pragma unroll
            for (int nt = 0; nt < 2; ++nt)
#pragma unroll
                for (int r = 0; r < 4; ++r)
                    smax[w][bi][nt * 16 + quad * 4 + r] = mx[bi][nt][r];
    }
    __syncthreads();
    // combine waves, then sum over the 32 query tokens
    if (t < BG * NQ) {
        int bi = t >> 5, n = t & 31;
        float v = fmaxf(fmaxf(smax[0][bi][n], smax[1][bi][n]),
                        fmaxf(smax[2][bi][n], smax[3][bi][n]));
#pragma unroll
        for (int o = 1; o < 32; o <<= 1) v += __shfl_xor(v, o);
        if (n == 0) scores[(bg * BG + bi) * BSZ + c] = v;
    }
}

// ---------------- finisher: combine both losses, write out directly ----------------
__global__ void finish_kernel(const float* __restrict__ scores, const float* __restrict__ svrow,
                              float* __restrict__ out) {
    int t = threadIdx.x;  // 64
    float pos = scores[t * BSZ + t];
    float neg = -1e30f;
    for (int cc = 0; cc < BSZ; ++cc)
        if (cc != t) neg = fmaxf(neg, scores[t * BSZ + cc]);
    float x = neg - pos;
    float sp = fmaxf(x, 0.f) + log1pf(expf(-fabsf(x)));   // stable softplus
    float sv = svrow[t];
#pragma unroll
    for (int o = 1; o < 64; o <<= 1) {
        sp += __shfl_xor(sp, o);
        sv += __shfl_xor(sv, o);
    }
    if (t == 0) out[0] = ALPHA * sv + (1.0f - ALPHA) * (sp * (1.0f / BSZ));
}

// ---------------- launch ----------------
extern "C" void kernel_launch(void* const* d_in, const int* in_sizes, int n_in,
                              void* d_out, int out_size, void* d_ws, size_t ws_size,
                              hipStream_t stream) {
    const float* q_single = (const float*)d_in[0];
    const float* d_single = (const float*)d_in[1];
    const float* q_multi  = (const float*)d_in[2];
    const float* d_multi  = (const float*)d_in[3];
    float* out = (float*)d_out;

    // workspace: qb (512 KB) | db (16 MB) | scores (16 KB) | svrow (256 B)
    unsigned short* qb = (unsigned short*)d_ws;
    unsigned short* db = (unsigned short*)((char*)d_ws + 524288);
    float* scores      = (float*)((char*)d_ws + 524288 + 16777216);
    float* svrow       = (float*)((char*)d_ws + 524288 + 16777216 + 16384);

    prep_kernel<<<CVT_BLOCKS + BSZ, 256, 0, stream>>>(q_multi, d_multi, q_single, d_single,
                                                      qb, db, svrow);
    multi_scores_kernel<<<dim3(16, 64), 256, 0, stream>>>(qb, db, scores);
    finish_kernel<<<1, 64, 0, stream>>>(scores, svrow, out);
}

// Round 3
// 160.442 us; speedup vs baseline: 1.1598x; 1.1598x over previous
//
#include <hip/hip_runtime.h>
#include <hip/hip_bf16.h>
#include <math.h>

// Sizes (fixed by the reference problem)
#define BSZ 64
#define DV  1024
#define NQ  32
#define NS  1024
#define DD  128

#define ALPHA 0.5f
#define TS   128            // s-rows per multi block
#define NSR  (NS / TS)      // 8 s-slices
#define ROWB 272            // LDS row stride bytes: 256B data + 16B pad (16B aligned)

typedef __attribute__((ext_vector_type(8))) short short8;   // 8 bf16 (4 VGPR) MFMA A/B frag
typedef __attribute__((ext_vector_type(4))) float floatx4;  // MFMA C/D frag

__device__ __forceinline__ unsigned short bf16_of(float x) {
    __hip_bfloat16 h = __float2bfloat16(x);
    return *(unsigned short*)&h;
}

// ---------------- prep: q_multi fp32->bf16 (blocks 0..63) + single-vector CE (blocks 64..127) ----
__global__ void prep_kernel(const float* __restrict__ qm,
                            const float* __restrict__ qs, const float* __restrict__ ds,
                            unsigned short* __restrict__ qb, float* __restrict__ svrow) {
    __shared__ float row[BSZ];
    if (blockIdx.x < 64) {
        const int QG = (BSZ * NQ * DD) / 4;   // 65536 float4 groups
        int idx = blockIdx.x * 256 + threadIdx.x;
#pragma unroll
        for (int it = 0; it < 4; ++it) {
            int g = idx + it * 16384;
            float4 v = ((const float4*)qm)[g];
            ushort4 u;
            u.x = bf16_of(v.x); u.y = bf16_of(v.y); u.z = bf16_of(v.z); u.w = bf16_of(v.w);
            *(ushort4*)(qb + g * 4) = u;
        }
    } else {
        int b = blockIdx.x - 64;             // 0..63
        int t = threadIdx.x;                 // 256
        int c = t >> 2, part = t & 3;
        const float4* qv = (const float4*)(qs + b * DV);
        const float4* dv = (const float4*)(ds + c * DV);
        float acc = 0.f;
        int k0 = part * 64;
#pragma unroll 8
        for (int k = k0; k < k0 + 64; ++k) {
            float4 a = qv[k], bb = dv[k];
            acc += a.x * bb.x + a.y * bb.y + a.z * bb.z + a.w * bb.w;
        }
        acc += __shfl_xor(acc, 1);
        acc += __shfl_xor(acc, 2);
        if (part == 0) row[c] = acc;
        __syncthreads();
        if (t < BSZ) {
            float v = row[t];
            float m = v;
#pragma unroll
            for (int o = 1; o < 64; o <<= 1) m = fmaxf(m, __shfl_xor(m, o));
            float e = expf(v - m);
#pragma unroll
            for (int o = 1; o < 64; o <<= 1) e += __shfl_xor(e, o);
            float lse = m + logf(e);
            if (t == 0) svrow[b] = lse - row[b];
        }
    }
}

// ---------------- multi: block=(c,sr) computes chunk-maxes for ALL 64 b vs d[c, sr*128..] ------
// d read ONCE device-wide (fp32, converted during LDS staging). q re-read from L2 (bf16, tiny).
// partial[sr][c][b][n] = max over this chunk's 128 s of Q[b,n,:].D[c,s,:]
__launch_bounds__(256, 2)
__global__ void multi_kernel(const unsigned short* __restrict__ qb,
                             const float* __restrict__ dm,
                             float* __restrict__ partial) {
    int c  = blockIdx.x;         // 0..63
    int sr = blockIdx.y;         // 0..7
    int t  = threadIdx.x;        // 256
    int w  = t >> 6;             // wave 0..3 (owns b-range [w*16, w*16+16))
    int l  = t & 63;
    int lane16 = l & 15;
    int quad   = (l >> 4) & 3;

    __shared__ __align__(16) unsigned char dch[TS * ROWB];   // 34816 B bf16 chunk

    // ---- stage d[c, sr*128 .. +128) fp32 -> bf16 LDS, fully coalesced ----
    {
        const float4* src = (const float4*)(dm + ((size_t)c * NS + sr * TS) * DD);
#pragma unroll
        for (int p = 0; p < 16; ++p) {
            int f = p * 256 + t;                    // float4 group 0..4095
            float4 v = src[f];
            ushort4 u;
            u.x = bf16_of(v.x); u.y = bf16_of(v.y); u.z = bf16_of(v.z); u.w = bf16_of(v.w);
            *(ushort4*)(dch + (f >> 5) * ROWB + (f & 31) * 8) = u;
        }
    }
    __syncthreads();

    // ---- B fragments for all 8 s-tiles, resident in regs: B[s=lane&15][k=quad*8+j] ----
    short8 bf[8][4];
#pragma unroll
    for (int st = 0; st < 8; ++st)
#pragma unroll
        for (int ks = 0; ks < 4; ++ks)
            bf[st][ks] = *(const short8*)(dch + (st * 16 + lane16) * ROWB + ks * 64 + quad * 16);

    float* pout = partial + (size_t)(sr * BSZ + c) * BSZ * NQ;

    short8 afA[8], afB[8];   // [nt*4+ks], double-buffered A frags
    auto loadaf = [&](short8* dst, int b) {
        const unsigned short* p2 = qb + ((size_t)b * NQ + lane16) * DD + quad * 8;
#pragma unroll
        for (int nt = 0; nt < 2; ++nt)
#pragma unroll
            for (int ks = 0; ks < 4; ++ks)
                dst[nt * 4 + ks] = *(const short8*)(p2 + nt * 16 * DD + ks * 32);
    };

    auto compute = [&](const short8* af, int b) {
        float mxv[2][4];
#pragma unroll
        for (int nt = 0; nt < 2; ++nt)
#pragma unroll
            for (int r = 0; r < 4; ++r) mxv[nt][r] = -1e30f;
#pragma unroll
        for (int sp = 0; sp < 4; ++sp) {           // st pairs: 4 tiles in flight
            floatx4 acc[2][2];
#pragma unroll
            for (int nt = 0; nt < 2; ++nt)
#pragma unroll
                for (int j = 0; j < 2; ++j) acc[nt][j] = (floatx4){0.f, 0.f, 0.f, 0.f};
#pragma unroll
            for (int ks = 0; ks < 4; ++ks)
#pragma unroll
                for (int nt = 0; nt < 2; ++nt)
#pragma unroll
                    for (int j = 0; j < 2; ++j)
                        acc[nt][j] = __builtin_amdgcn_mfma_f32_16x16x32_bf16(
                            af[nt * 4 + ks], bf[sp * 2 + j][ks], acc[nt][j], 0, 0, 0);
#pragma unroll
            for (int nt = 0; nt < 2; ++nt)
#pragma unroll
                for (int j = 0; j < 2; ++j)
#pragma unroll
                    for (int r = 0; r < 4; ++r)
                        mxv[nt][r] = fmaxf(mxv[nt][r], acc[nt][j][r]);
        }
        // max over the 16 s-columns held across lane16
#pragma unroll
        for (int nt = 0; nt < 2; ++nt)
#pragma unroll
            for (int r = 0; r < 4; ++r) {
                float v = mxv[nt][r];
                v = fmaxf(v, __shfl_xor(v, 1));
                v = fmaxf(v, __shfl_xor(v, 2));
                v = fmaxf(v, __shfl_xor(v, 4));
                v = fmaxf(v, __shfl_xor(v, 8));
                mxv[nt][r] = v;
            }
        if (lane16 == 0) {       // lanes 0,16,32,48 (quad 0..3): n = nt*16 + quad*4 + r
            float* o = pout + (size_t)b * NQ + quad * 4;
#pragma unroll
            for (int nt = 0; nt < 2; ++nt)
#pragma unroll
                for (int r = 0; r < 4; ++r) o[nt * 16 + r] = mxv[nt][r];
        }
    };

    int b0 = w * 16;
    loadaf(afA, b0);
    for (int i = 0; i < 16; i += 2) {
        loadaf(afB, b0 + i + 1);
        compute(afA, b0 + i);
        if (i + 2 < 16) loadaf(afA, b0 + i + 2);
        compute(afB, b0 + i + 1);
    }
}

// ---------------- reduce: scores[b][c] = sum_n max_sr partial[sr][c][b][n] ----------------
__global__ void reduce_kernel(const float* __restrict__ partial, float* __restrict__ scores) {
    int p = blockIdx.x * 256 + threadIdx.x;   // 0..4095
    int c = p >> 6, b = p & 63;
    float4 mx[8];
#pragma unroll
    for (int j = 0; j < 8; ++j) mx[j] = make_float4(-1e30f, -1e30f, -1e30f, -1e30f);
#pragma unroll
    for (int sr = 0; sr < NSR; ++sr) {
        const float4* q = (const float4*)(partial + ((size_t)(sr * BSZ + c) * BSZ + b) * NQ);
#pragma unroll
        for (int j = 0; j < 8; ++j) {
            float4 v = q[j];
            mx[j].x = fmaxf(mx[j].x, v.x); mx[j].y = fmaxf(mx[j].y, v.y);
            mx[j].z = fmaxf(mx[j].z, v.z); mx[j].w = fmaxf(mx[j].w, v.w);
        }
    }
    float s = 0.f;
#pragma unroll
    for (int j = 0; j < 8; ++j) s += mx[j].x + mx[j].y + mx[j].z + mx[j].w;
    scores[b * BSZ + c] = s;
}

// ---------------- finisher: combine both losses ----------------
__global__ void finish_kernel(const float* __restrict__ scores, const float* __restrict__ svrow,
                              float* __restrict__ out) {
    int t = threadIdx.x;  // 64
    float pos = scores[t * BSZ + t];
    float neg = -1e30f;
    for (int cc = 0; cc < BSZ; ++cc)
        if (cc != t) neg = fmaxf(neg, scores[t * BSZ + cc]);
    float x = neg - pos;
    float sp = fmaxf(x, 0.f) + log1pf(expf(-fabsf(x)));   // stable softplus
    float sv = svrow[t];
#pragma unroll
    for (int o = 1; o < 64; o <<= 1) {
        sp += __shfl_xor(sp, o);
        sv += __shfl_xor(sv, o);
    }
    if (t == 0) out[0] = ALPHA * sv + (1.0f - ALPHA) * (sp * (1.0f / BSZ));
}

// ---------------- launch ----------------
extern "C" void kernel_launch(void* const* d_in, const int* in_sizes, int n_in,
                              void* d_out, int out_size, void* d_ws, size_t ws_size,
                              hipStream_t stream) {
    const float* q_single = (const float*)d_in[0];
    const float* d_single = (const float*)d_in[1];
    const float* q_multi  = (const float*)d_in[2];
    const float* d_multi  = (const float*)d_in[3];
    float* out = (float*)d_out;

    // ws: qb 512KB | partial 4MB | scores 16KB | svrow 256B
    unsigned short* qb = (unsigned short*)d_ws;
    float* partial     = (float*)((char*)d_ws + 524288);
    float* scores      = (float*)((char*)d_ws + 524288 + 4194304);
    float* svrow       = (float*)((char*)d_ws + 524288 + 4194304 + 16384);

    prep_kernel<<<128, 256, 0, stream>>>(q_multi, q_single, d_single, qb, svrow);
    multi_kernel<<<dim3(BSZ, NSR), 256, 0, stream>>>(qb, d_multi, partial);
    reduce_kernel<<<16, 256, 0, stream>>>(partial, scores);
    finish_kernel<<<1, 64, 0, stream>>>(scores, svrow, out);
}